// Round 6
// baseline (1541.032 us; speedup 1.0000x reference)
//
#include <hip/hip_runtime.h>
#include <stdint.h>
#include <stddef.h>

#define CH     512
#define TT     32
#define NBLK   32
#define NBATCH 32
#define NTHR   1024   // 16 waves: 0-7 compute (64 ch each), 8-15 x/out movers

// ---- transpose: WT[j][c] = W[c][j] (row j = presyn channel, 2 KiB/row) ----
__global__ __launch_bounds__(256) void transpose_k(const float* __restrict__ W,
                                                   float* __restrict__ WT) {
    __shared__ float tile[64][65];
    const int bx = blockIdx.x & 7, by = blockIdx.x >> 3;
    const int lx = threadIdx.x & 63, ly = threadIdx.x >> 6;
    for (int r = ly; r < 64; r += 4)
        tile[r][lx] = W[(size_t)(by * 64 + r) * CH + bx * 64 + lx];
    __syncthreads();
    for (int r = ly; r < 64; r += 4)
        WT[(size_t)(bx * 64 + r) * CH + by * 64 + lx] = tile[lx][r];
}

// Single-WG-per-batch: the whole 512-channel recurrent ring lives in one WG.
// No inter-WG communication at all: spike list + counts in LDS, handoff via
// __syncthreads (2 barriers/block). Entry = (ch9<<5)|t5, per-chunk segments
// sorted by (t, lane) -> same-t spikes accumulate in ascending-channel order
// (matches the einsum-over-j semantics of the reference).
// buf[2] ping-pong: buf[n&1] = x(n) seed + spike gather target + dynamics
// input; waves 8-15 refill buf[(n+1)&1] with x(n+1) during dynamics(n).
__global__ __launch_bounds__(NTHR, 4) void snn_kernel(
    const float* __restrict__ x,
    const float* __restrict__ beta_raw,
    const float* __restrict__ WT,
    const float* __restrict__ p_raw,
    const float* __restrict__ b_raw,
    float*     __restrict__ out)
{
    __shared__ float buf[2][CH * 33];      // 2 x 66 KiB, stride 33 (bank-clean)
    __shared__ __align__(16) int ent[512]; // per-chunk segments: ent[g*64 + rank]
    __shared__ int cnt_lds[8];
    __shared__ int tf2[2][CH];             // t_first per channel, parity-buffered

    const int b   = blockIdx.x;            // one WG per batch
    const int tid = threadIdx.x;
    const int l   = tid & 63;
    const int g   = tid >> 6;              // wave 0..15
    const size_t base = ((size_t)b) << 19; // b*CH*1024 floats

    const int c  = (g << 6) + l;           // waves 0-7: owned channel
    const int cc = c & (CH - 1);           // safe param index for waves 8-15
    const float beta  = fminf(fmaxf(beta_raw[cc], 0.001f), 0.999f);
    const float p     = fminf(fabsf(p_raw[cc]), 0.999f);
    const float bb    = fminf(fmaxf(fabsf(b_raw[cc]), 0.001f), 1.0f);
    const float inv_p = 1.0f / p;
    float p32; { float t2 = p*p, t4 = t2*t2, t8 = t4*t4, t16 = t8*t8; p32 = t16*t16; }
    float a_mult = 0.f, v_init = 0.f;
    int   zero_start = 0;
    const unsigned long long lowmask = (1ull << l) - 1ull;

    // ---- pre-loop: waves 8-15 fill buf[0] with x block 0 ----
    if (g >= 8) {
        const int slot = tid - 512, q = slot & 7, ch0 = slot >> 3;
        #pragma unroll
        for (int it = 0; it < 8; ++it) {
            const int ch = ch0 + (it << 6);
            const float4 v = *(const float4*)(x + base + ((size_t)ch << 10) + (q << 2));
            float* d = &buf[0][ch * 33 + (q << 2)];
            d[0] = v.x; d[1] = v.y; d[2] = v.z; d[3] = v.w;
        }
    }
    __syncthreads();

    #pragma unroll 1
    for (int n = 0; n < NBLK; ++n) {
        float* bufc = &buf[n & 1][0];
        float4 xs[8];

        // ---- phase G: waves 0-7 gather spikes(n-1) into bufc (x-preseeded)
        //              waves 8-15: out(n-1) store + x(n+1) global->reg ----
        if (g >= 8) {
            const int slot = tid - 512, q = slot & 7, ch0 = slot >> 3;
            if (n > 0) {
                #pragma unroll
                for (int it = 0; it < 8; ++it) {
                    const int ch = ch0 + (it << 6);
                    const int tf = tf2[(n - 1) & 1][ch];
                    const int t0 = q << 2;
                    float4 v;
                    v.x = (t0     == tf) ? 1.f : 0.f;
                    v.y = (t0 + 1 == tf) ? 1.f : 0.f;
                    v.z = (t0 + 2 == tf) ? 1.f : 0.f;
                    v.w = (t0 + 3 == tf) ? 1.f : 0.f;
                    *(float4*)(out + base + ((size_t)ch << 10) + ((n - 1) << 5) + t0) = v;
                }
            }
            if (n + 1 < NBLK) {
                #pragma unroll
                for (int it = 0; it < 8; ++it) {
                    const int ch = ch0 + (it << 6);
                    xs[it] = *(const float4*)(x + base + ((size_t)ch << 10) + ((n + 1) << 5) + (q << 2));
                }
            }
        } else if (n > 0) {
            const char* WTb = (const char*)WT;
            const int col4 = c << 2;
            float* myrec = &bufc[c * 33];
            float acc = 0.f; int cur_t = -1;
            #pragma unroll 1
            for (int j = 0; j < 8; ++j) {
                const int cj = cnt_lds[j];
                const int Ew = ent[(j << 6) + l];   // lane l holds rank-l entry
                for (int r0 = 0; r0 < cj; r0 += 16) {
                    int T[16]; float F[16];
                    #pragma unroll
                    for (int k = 0; k < 16; ++k) {
                        const int r = r0 + k;
                        const int e = __builtin_amdgcn_readlane(Ew, r & 63);
                        const bool ok = r < cj;
                        T[k] = ok ? (e & 31) : -1;
                        const int off = ok ? ((e & ~31) << 6) : 0;   // ch*2048
                        F[k] = *(const float*)(WTb + off + col4);
                    }
                    #pragma unroll
                    for (int k = 0; k < 16; ++k) {
                        if (T[k] >= 0) {
                            if (T[k] != cur_t) { if (cur_t >= 0) myrec[cur_t] += acc; acc = 0.f; cur_t = T[k]; }
                            acc += F[k];
                        }
                    }
                }
            }
            if (cur_t >= 0) myrec[cur_t] += acc;
        }
        __syncthreads();   // Bg: bufc complete

        // ---- phase D: waves 0-7 dynamics + ballot-sort -> ent/cnt/tf
        //              waves 8-15: reg -> buf[(n+1)&1] x-seed ----
        if (g < 8) {
            float mem = 0.f, pc = p, pca = p;
            int t_first = -1;
            #pragma unroll
            for (int t = 0; t < TT; ++t) {
                const float rv = bufc[c * 33 + t];
                float cur = (t >= zero_start) ? rv : 0.f;
                if (t == 0) cur += beta * v_init;
                mem = beta * mem + cur;
                const float vth = 1.f + bb * pc * a_mult;
                if ((mem - vth > 0.f) && t_first < 0) { t_first = t; pca = pc; }
                pc *= p;
            }
            if (t_first >= 0) {
                float pd = 1.f;
                for (int m = 31 - t_first; m > 0; --m) pd *= p;
                a_mult = (pca * a_mult + inv_p) * pd;
                v_init = 0.f; zero_start = t_first;
            } else {
                a_mult = p32 * a_mult;
                v_init = mem; zero_start = 0;
            }
            tf2[n & 1][c] = t_first;
            // per-wave (64-ch chunk) sort by (t, lane): rank via ballot prefix
            unsigned prefc = 0; int mypos = 0;
            #pragma unroll
            for (int t = 0; t < TT; ++t) {
                const unsigned long long bal = __ballot(t_first == t);
                if (t_first == t) mypos = (int)prefc + (int)__popcll(bal & lowmask);
                prefc += (unsigned)__popcll(bal);
            }
            if (t_first >= 0) ent[(g << 6) + mypos] = (c << 5) | t_first;
            if (l == 0) cnt_lds[g] = (int)prefc;
        } else {
            if (n + 1 < NBLK) {
                const int slot = tid - 512, q = slot & 7, ch0 = slot >> 3;
                float* bufn = &buf[(n + 1) & 1][0];
                #pragma unroll
                for (int it = 0; it < 8; ++it) {
                    const int ch = ch0 + (it << 6);
                    float* d = &bufn[ch * 33 + (q << 2)];
                    d[0] = xs[it].x; d[1] = xs[it].y; d[2] = xs[it].z; d[3] = xs[it].w;
                }
            }
        }
        __syncthreads();   // Bd: ent/cnt/tf ready; buf[(n+1)&1] seeded
    }

    // ---- final out block 31 (all 16 waves, 4 channels' worth each) ----
    {
        const int q = tid & 7, ch0 = tid >> 3;   // ch0 in [0,128)
        #pragma unroll
        for (int it = 0; it < 4; ++it) {
            const int ch = ch0 + (it << 7);
            const int tf = tf2[1][ch];           // 31 & 1 == 1
            const int t0 = q << 2;
            float4 v;
            v.x = (t0     == tf) ? 1.f : 0.f;
            v.y = (t0 + 1 == tf) ? 1.f : 0.f;
            v.z = (t0 + 2 == tf) ? 1.f : 0.f;
            v.w = (t0 + 3 == tf) ? 1.f : 0.f;
            *(float4*)(out + base + ((size_t)ch << 10) + (31 << 5) + t0) = v;
        }
    }
}

extern "C" void kernel_launch(void* const* d_in, const int* in_sizes, int n_in,
                              void* d_out, int out_size, void* d_ws, size_t ws_size,
                              hipStream_t stream) {
    (void)in_sizes; (void)n_in; (void)out_size;
    const float* x   = (const float*)d_in[0];
    const float* br  = (const float*)d_in[1];
    const float* W   = (const float*)d_in[2];
    const float* pr  = (const float*)d_in[3];
    const float* bbr = (const float*)d_in[4];
    float* out = (float*)d_out;

    const size_t wt_bytes = (size_t)CH * CH * sizeof(float);   // 1 MiB
    if (ws_size < wt_bytes) return;
    float* WT = (float*)d_ws;

    transpose_k<<<64, 256, 0, stream>>>(W, WT);
    snn_kernel<<<NBATCH, NTHR, 0, stream>>>(x, br, WT, pr, bbr, out);
}

// Round 8
// 936.446 us; speedup vs baseline: 1.6456x; 1.6456x over previous
//
#include <hip/hip_runtime.h>
#include <stdint.h>
#include <stddef.h>

#define CH     512
#define TT     32
#define NBLK   32
#define NBATCH 32
#define NPAIR  16     // batch pairs; WG serves one pair's 64-ch chunk
#define NCHUNK 8      // chunks (WGs) per batch ring
#define NTHR   1024   // 16 waves: 0-7 compute, 8-15 movers

// ---- transpose: WT[j][c] = W[c][j] (row j = presyn channel, 2 KiB/row) ----
__global__ __launch_bounds__(256) void transpose_k(const float* __restrict__ W,
                                                   float* __restrict__ WT) {
    __shared__ float tile[64][65];
    const int bx = blockIdx.x & 7, by = blockIdx.x >> 3;
    const int lx = threadIdx.x & 63, ly = threadIdx.x >> 6;
    for (int r = ly; r < 64; r += 4)
        tile[r][lx] = W[(size_t)(by * 64 + r) * CH + bx * 64 + lx];
    __syncthreads();
    for (int r = ly; r < 64; r += 4)
        WT[(size_t)(bx * 64 + r) * CH + by * 64 + lx] = tile[lx][r];
}

// DUAL-BATCH interleave of the proven 443-us kernel: each WG runs the full
// per-block pipeline for TWO independent batches (A then B). The B half-cycle
// sits between publish-A(n) and poll-A(n+1), hiding the inter-WG handoff
// latency (publish -> MALL visibility -> detect) that profiling shows costs
// ~8-9 us/block of idle in the single-batch ring. Per-batch protocol,
// summation order, and dynamics are VERBATIM the 443 kernel (absmax 0.0):
// published word = two 16b entries [tag4|t6|ch6], t=63 = no spike; fence-free
// (tag lives in the same 32b word as the data -> single-word atomicity is the
// ordering); per-word latched poll; private per-wave scatter + segment gather.
#define TAGOK(v) (((((v) >> 12) & 15u) == want) && ((((v) >> 28) & 15u) == want))

#define PHASE_C(pgX, rec8X, tfX, xsX, baseX)                                        \
    {                                                                               \
    if (g >= 8) {                                                                   \
        const int slot = tid - 512;                                                 \
        const int ch = slot >> 3, q = slot & 7;                                     \
        if (n + 1 < NBLK)                                                           \
            xsX = *(const float4*)(x + baseX + ((size_t)((kown << 6) + ch) << 10) + ((n + 1) << 5) + (q << 2)); \
        if (n > 0) {                                                                \
            const int tf = tfX[ch];                                                 \
            const int t0 = q << 2;                                                  \
            float4 v;                                                               \
            v.x = (t0     == tf) ? 1.f : 0.f;                                       \
            v.y = (t0 + 1 == tf) ? 1.f : 0.f;                                       \
            v.z = (t0 + 2 == tf) ? 1.f : 0.f;                                       \
            v.w = (t0 + 3 == tf) ? 1.f : 0.f;                                       \
            *(float4*)(out + baseX + ((size_t)((kown << 6) + ch) << 10) + ((n - 1) << 5) + t0) = v; \
        }                                                                           \
    } else if (n > 0) {                                                             \
        const unsigned want = (unsigned)((n - 1) & 15);                             \
        unsigned w0 = 0, w1 = 0, w2 = 0, w3 = 0;                                    \
        {                                                                           \
            bool d0 = false, d1 = false, d2 = false, d3 = false;                    \
            while (true) {                                                          \
                if (!d0) { const unsigned v = (unsigned)__hip_atomic_load(pgX + l,       __ATOMIC_RELAXED, __HIP_MEMORY_SCOPE_AGENT); if (TAGOK(v)) { w0 = v; d0 = true; } } \
                if (!d1) { const unsigned v = (unsigned)__hip_atomic_load(pgX + 64 + l,  __ATOMIC_RELAXED, __HIP_MEMORY_SCOPE_AGENT); if (TAGOK(v)) { w1 = v; d1 = true; } } \
                if (!d2) { const unsigned v = (unsigned)__hip_atomic_load(pgX + 128 + l, __ATOMIC_RELAXED, __HIP_MEMORY_SCOPE_AGENT); if (TAGOK(v)) { w2 = v; d2 = true; } } \
                if (!d3) { const unsigned v = (unsigned)__hip_atomic_load(pgX + 192 + l, __ATOMIC_RELAXED, __HIP_MEMORY_SCOPE_AGENT); if (TAGOK(v)) { w3 = v; d3 = true; } } \
                if (d0 && d1 && d2 && d3) break;                                    \
                __builtin_amdgcn_s_sleep(1);                                        \
            }                                                                       \
        }                                                                           \
        const unsigned long long LO32 = 0xFFFFFFFFull;                              \
        const int e00 = (int)(w0 & 0xFFFFu), e01 = (int)((w0 >> 16) & 0xFFFFu);     \
        const int e10 = (int)(w1 & 0xFFFFu), e11 = (int)((w1 >> 16) & 0xFFFFu);     \
        const int e20 = (int)(w2 & 0xFFFFu), e21 = (int)((w2 >> 16) & 0xFFFFu);     \
        const int e30 = (int)(w3 & 0xFFFFu), e31 = (int)((w3 >> 16) & 0xFFFFu);     \
        const int s00 = ((e00 >> 6) & 63) != 63, s01 = ((e01 >> 6) & 63) != 63;     \
        const int s10 = ((e10 >> 6) & 63) != 63, s11 = ((e11 >> 6) & 63) != 63;     \
        const int s20 = ((e20 >> 6) & 63) != 63, s21 = ((e21 >> 6) & 63) != 63;     \
        const int s30 = ((e30 >> 6) & 63) != 63, s31 = ((e31 >> 6) & 63) != 63;     \
        const unsigned long long b00 = __ballot(s00 != 0), b01 = __ballot(s01 != 0); \
        const unsigned long long b10 = __ballot(s10 != 0), b11 = __ballot(s11 != 0); \
        const unsigned long long b20 = __ballot(s20 != 0), b21 = __ballot(s21 != 0); \
        const unsigned long long b30 = __ballot(s30 != 0), b31 = __ballot(s31 != 0); \
        const int cnt0 = (int)__popcll(b00 & LO32) + (int)__popcll(b01 & LO32);     \
        const int cnt1 = (int)__popcll(b00 >> 32)  + (int)__popcll(b01 >> 32);      \
        const int cnt2 = (int)__popcll(b10 & LO32) + (int)__popcll(b11 & LO32);     \
        const int cnt3 = (int)__popcll(b10 >> 32)  + (int)__popcll(b11 >> 32);      \
        const int cnt4 = (int)__popcll(b20 & LO32) + (int)__popcll(b21 & LO32);     \
        const int cnt5 = (int)__popcll(b20 >> 32)  + (int)__popcll(b21 >> 32);      \
        const int cnt6 = (int)__popcll(b30 & LO32) + (int)__popcll(b31 & LO32);     \
        const int cnt7 = (int)__popcll(b30 >> 32)  + (int)__popcll(b31 >> 32);      \
        const int pf1 = cnt0;                                                       \
        const int pf2 = pf1 + cnt1;                                                 \
        const int pf3 = pf2 + cnt2;                                                 \
        const int pf4 = pf3 + cnt3;                                                 \
        const int pf5 = pf4 + cnt4;                                                 \
        const int pf6 = pf5 + cnt5;                                                 \
        const int pf7 = pf6 + cnt6;                                                 \
        const int L   = pf7 + cnt7;                                                 \
        const int hi = (l >> 5) & 1;                                                \
        const int j2 = (l & 31) << 1;                                               \
        int* entW = &ent8[g][0];                                                    \
        {                                                                           \
            const int pc_ = hi ? pf1 : 0;    const int cb = (0 + hi) << 6;          \
            if (s00) entW[pc_ + j2]     = ((cb | (e00 & 63)) << 5) | ((e00 >> 6) & 31); \
            if (s01) entW[pc_ + j2 + 1] = ((cb | (e01 & 63)) << 5) | ((e01 >> 6) & 31); \
        }                                                                           \
        {                                                                           \
            const int pc_ = hi ? pf3 : pf2;  const int cb = (2 + hi) << 6;          \
            if (s10) entW[pc_ + j2]     = ((cb | (e10 & 63)) << 5) | ((e10 >> 6) & 31); \
            if (s11) entW[pc_ + j2 + 1] = ((cb | (e11 & 63)) << 5) | ((e11 >> 6) & 31); \
        }                                                                           \
        {                                                                           \
            const int pc_ = hi ? pf5 : pf4;  const int cb = (4 + hi) << 6;          \
            if (s20) entW[pc_ + j2]     = ((cb | (e20 & 63)) << 5) | ((e20 >> 6) & 31); \
            if (s21) entW[pc_ + j2 + 1] = ((cb | (e21 & 63)) << 5) | ((e21 >> 6) & 31); \
        }                                                                           \
        {                                                                           \
            const int pc_ = hi ? pf7 : pf6;  const int cb = (6 + hi) << 6;          \
            if (s30) entW[pc_ + j2]     = ((cb | (e30 & 63)) << 5) | ((e30 >> 6) & 31); \
            if (s31) entW[pc_ + j2 + 1] = ((cb | (e31 & 63)) << 5) | ((e31 >> 6) & 31); \
        }                                                                           \
        __threadfence_block();                                                      \
        if (L > 0) {                                                                \
            const char* WTb = (const char*)WT;                                      \
            const int col4 = ((kown << 6) + l) << 2;                                \
            float* myrec = &rec8X[g][l * 33];                                       \
            float acc = 0.f; int cur_t = -1;                                        \
            _Pragma("unroll")                                                       \
            for (int s = 0; s < 8; ++s) {                                           \
                const int segbase = s << 6;                                         \
                if (segbase < L) {                                                  \
                    const int ve = entW[segbase + l];                               \
                    int S[8]; float F[8];                                           \
                    _Pragma("unroll")                                               \
                    for (int k = 0; k < 8; ++k) {                                   \
                        const int idx = segbase + g + (k << 3);                     \
                        int sv = __builtin_amdgcn_readlane(ve, g + (k << 3));       \
                        const int ok = idx < L;                                     \
                        S[k] = ok ? sv : -1;                                        \
                        sv = ok ? sv : 0;                                           \
                        F[k] = *(const float*)(WTb + ((sv & 0xFFE0) << 6) + col4);  \
                    }                                                               \
                    _Pragma("unroll")                                               \
                    for (int k = 0; k < 8; ++k) {                                   \
                        if (S[k] >= 0) {                                            \
                            const int t = S[k] & 31;                                \
                            if (t != cur_t) { if (cur_t >= 0) myrec[cur_t] += acc; acc = 0.f; cur_t = t; } \
                            acc += F[k];                                            \
                        }                                                           \
                    }                                                               \
                }                                                                   \
            }                                                                       \
            if (cur_t >= 0) myrec[cur_t] += acc;                                    \
        }                                                                           \
    }                                                                               \
    }

#define PHASE_D(rec8X)                                                              \
    {                                                                               \
    _Pragma("unroll")                                                               \
    for (int r = 0; r < 2; ++r) {                                                   \
        const int e = tid + (r << 10);                                              \
        const int idx = ((e >> 5) * 33) + (e & 31);                                 \
        rec_tot[idx] = ((rec8X[0][idx] + rec8X[1][idx]) + (rec8X[2][idx] + rec8X[3][idx])) \
                     + ((rec8X[4][idx] + rec8X[5][idx]) + (rec8X[6][idx] + rec8X[7][idx])); \
    }                                                                               \
    }

#define PHASE_E(pgX, rec8X, tfX, xsX, a_mX, v_iX, zsX)                              \
    {                                                                               \
    if (g == 0) {                                                                   \
        __builtin_amdgcn_s_setprio(1);                                              \
        float mem = 0.f, pc = p, pca = p;                                           \
        int t_first = -1, mypos = 0;                                                \
        unsigned prefc = 0;                                                         \
        _Pragma("unroll")                                                           \
        for (int t = 0; t < TT; ++t) {                                              \
            const float rv = rec_tot[l * 33 + t];                                   \
            float cur = (t >= zsX) ? rv : 0.f;                                      \
            if (t == 0) cur += beta * v_iX;                                         \
            mem = beta * mem + cur;                                                 \
            const float vth = 1.f + bb * pc * a_mX;                                 \
            const bool fire = (mem - vth > 0.f) && (t_first < 0);                   \
            const unsigned long long bal = __ballot(fire);                          \
            if (fire) { t_first = t; pca = pc; mypos = (int)prefc + (int)__popcll(bal & lowmask); } \
            prefc += (unsigned)__popcll(bal);                                       \
            pc *= p;                                                                \
        }                                                                           \
        if (t_first >= 0) {                                                         \
            float pd = 1.f;                                                         \
            for (int m = 31 - t_first; m > 0; --m) pd *= p;                         \
            a_mX = (pca * a_mX + inv_p) * pd;                                       \
            v_iX = 0.f; zsX = t_first;                                              \
        } else {                                                                    \
            a_mX = p32 * a_mX;                                                      \
            v_iX = mem; zsX = 0;                                                    \
        }                                                                           \
        tfX[l] = t_first;                                                           \
        if (n + 1 < NBLK) {                                                         \
            const bool sp = (t_first >= 0);                                         \
            const unsigned long long balS = __ballot(sp);                           \
            const int cntS = (int)prefc;                                            \
            if (!sp) mypos = cntS + (int)__popcll(~balS & lowmask);                  \
            const int tval = sp ? t_first : 63;                                     \
            tmp16[mypos] = ((n & 15) << 12) | (tval << 6) | l;                      \
            __threadfence_block();                                                  \
            if (l < 32) {                                                           \
                const int wlo = tmp16[l << 1];                                      \
                const int whi = tmp16[(l << 1) | 1];                                \
                __hip_atomic_store(pgX + (kown << 5) + l, wlo | (whi << 16),        \
                                   __ATOMIC_RELAXED, __HIP_MEMORY_SCOPE_AGENT);     \
            }                                                                       \
        }                                                                           \
        __builtin_amdgcn_s_setprio(0);                                              \
    } else if (g >= 8) {                                                            \
        if (n + 1 < NBLK) {                                                         \
            const int slot = tid - 512;                                             \
            const int ch = slot >> 3, q = slot & 7;                                 \
            float* d = &rec8X[0][ch * 33 + (q << 2)];                               \
            d[0] = xsX.x; d[1] = xsX.y; d[2] = xsX.z; d[3] = xsX.w;                 \
        }                                                                           \
    } else {                                                                        \
        if (n + 1 < NBLK) {                                                         \
            const int t0 = tid - 64;                                                \
            _Pragma("unroll")                                                       \
            for (int z = 0; z < 33; ++z)                                            \
                (&rec8X[1][0])[t0 + 448 * z] = 0.f;                                 \
        }                                                                           \
    }                                                                               \
    }

__global__ __launch_bounds__(NTHR, 4) void snn_kernel(
    const float* __restrict__ x,
    const float* __restrict__ beta_raw,
    const float* __restrict__ WT,
    const float* __restrict__ p_raw,
    const float* __restrict__ b_raw,
    int*       __restrict__ ent_g,     // [NBATCH][256] tagged words
    float*     __restrict__ out)
{
    __shared__ float rec8A[8][2112];   // 66 KiB  batch A partials (rec8A[0] x-seeded)
    __shared__ float rec8B[8][2112];   // 66 KiB  batch B partials
    __shared__ float rec_tot[2112];    // shared reduce target (A/B barrier-separated)
    __shared__ int   ent8[8][512];     // shared per-wave scatter lists (per-phase)
    __shared__ int   tfA[64], tfB[64];
    __shared__ int   tmp16[64];        // producer sort scratch (wave 0 only)

    const int bidx = blockIdx.x;
    const int pb   = bidx & (NPAIR - 1);    // batch pair; ring of 8 WGs on one XCD
    const int kown = bidx >> 4;             // channel chunk 0..7
    const int bA   = pb << 1, bB = bA | 1;
    const int tid  = threadIdx.x;
    const int l    = tid & 63;
    const int g    = tid >> 6;              // wave 0..15
    const size_t baseA = ((size_t)bA) << 19;
    const size_t baseB = ((size_t)bB) << 19;
    int* pgA = ent_g + (bA << 8);
    int* pgB = ent_g + (bB << 8);

    const int c = (kown << 6) + l;          // wave0-lane channel (params shared A/B)
    const float beta  = fminf(fmaxf(beta_raw[c], 0.001f), 0.999f);
    const float p     = fminf(fabsf(p_raw[c]), 0.999f);
    const float bb    = fminf(fmaxf(fabsf(b_raw[c]), 0.001f), 1.0f);
    const float inv_p = 1.0f / p;
    float p32; { float t2 = p*p, t4 = t2*t2, t8 = t4*t4, t16 = t8*t8; p32 = t16*t16; }
    float a_mA = 0.f, v_iA = 0.f; int zsA = 0;
    float a_mB = 0.f, v_iB = 0.f; int zsB = 0;
    const unsigned long long lowmask = (1ull << l) - 1ull;

    // ---- pre-loop: seed rec8A[0]/rec8B[0] with x block 0; zero partials ----
    {
        const int slot = tid & 511, ch = slot >> 3, q = slot & 7;
        const size_t bx = (tid < 512) ? baseA : baseB;
        float* dst = (tid < 512) ? &rec8A[0][0] : &rec8B[0][0];
        const float4 v = *(const float4*)(x + bx + ((size_t)((kown << 6) + ch) << 10) + (q << 2));
        float* d = dst + ch * 33 + (q << 2);
        d[0] = v.x; d[1] = v.y; d[2] = v.z; d[3] = v.w;
    }
    #pragma unroll
    for (int z = 0; z < 15; ++z) {
        const int k = tid + (z << 10);
        if (k < 14784) { (&rec8A[1][0])[k] = 0.f; (&rec8B[1][0])[k] = 0.f; }
    }
    __syncthreads();

    #pragma unroll 1
    for (int n = 0; n < NBLK; ++n) {
        float4 xsA, xsB;
        // ---- batch A half-cycle ----
        PHASE_C(pgA, rec8A, tfA, xsA, baseA)
        __syncthreads();
        PHASE_D(rec8A)
        __syncthreads();
        PHASE_E(pgA, rec8A, tfA, xsA, a_mA, v_iA, zsA)
        __syncthreads();
        // ---- batch B half-cycle (fills A's handoff latency) ----
        PHASE_C(pgB, rec8B, tfB, xsB, baseB)
        __syncthreads();
        PHASE_D(rec8B)
        __syncthreads();
        PHASE_E(pgB, rec8B, tfB, xsB, a_mB, v_iB, zsB)
        __syncthreads();
    }

    // ---- final out block 31, both batches ----
    {
        const int slot = tid & 511, ch = slot >> 3, q = slot & 7;
        const int tf = (tid < 512) ? tfA[ch] : tfB[ch];
        const size_t bx = (tid < 512) ? baseA : baseB;
        const int t0 = q << 2;
        float4 v;
        v.x = (t0     == tf) ? 1.f : 0.f;
        v.y = (t0 + 1 == tf) ? 1.f : 0.f;
        v.z = (t0 + 2 == tf) ? 1.f : 0.f;
        v.w = (t0 + 3 == tf) ? 1.f : 0.f;
        *(float4*)(out + bx + ((size_t)((kown << 6) + ch) << 10) + (31 << 5) + t0) = v;
    }
}

extern "C" void kernel_launch(void* const* d_in, const int* in_sizes, int n_in,
                              void* d_out, int out_size, void* d_ws, size_t ws_size,
                              hipStream_t stream) {
    (void)in_sizes; (void)n_in; (void)out_size;
    const float* x   = (const float*)d_in[0];
    const float* br  = (const float*)d_in[1];
    const float* W   = (const float*)d_in[2];
    const float* pr  = (const float*)d_in[3];
    const float* bbr = (const float*)d_in[4];
    float* out = (float*)d_out;

    const size_t wt_bytes  = (size_t)CH * CH * sizeof(float);     // 1 MiB
    const size_t ent_bytes = (size_t)NBATCH * 256 * sizeof(int);  // 32 KiB
    if (ws_size < wt_bytes + ent_bytes) return;

    float* WT    = (float*)d_ws;
    int*   ent_g = (int*)((char*)d_ws + wt_bytes);
    // no memset: 0xAA poison tag (10) never matches first wanted tag (0),
    // and every slot is rewritten each step thereafter (proven protocol)

    transpose_k<<<64, 256, 0, stream>>>(W, WT);
    snn_kernel<<<NPAIR * NCHUNK, NTHR, 0, stream>>>(x, br, WT, pr, bbr, ent_g, out);
}